// Round 11
// baseline (372.106 us; speedup 1.0000x reference)
//
#include <hip/hip_runtime.h>

#define B_   16
#define C_   256
#define H_   48
#define W_   48
#define N_   (H_ * W_)   // 2304
#define KNN  8

#define NG   (N_ / 32)   // 72 row-groups per sample
#define NT   17          // K-chunks of 16: 256 data + 16 augment (e1,e2,+512,zeros)
#define FRAG 512         // u16 elements per (g,t) fragment block (64 lanes x 8)
#define MPRE 10          // prefilter depth per (wave,lh) subset
#define NCAND 20         // merged candidate union per row

typedef __attribute__((ext_vector_type(8)))  short bf16x8;
typedef __attribute__((ext_vector_type(8)))  unsigned short u16x8;
typedef __attribute__((ext_vector_type(16))) float f32x16;

__device__ __forceinline__ unsigned short f2bf(float f) {
    unsigned int u = __float_as_uint(f);
    u = (u + 0x7FFF + ((u >> 16) & 1)) >> 16;   // RNE
    return (unsigned short)u;
}
__device__ __forceinline__ float bf2f(unsigned short h) {
    return __uint_as_float(((unsigned int)h) << 16);
}
__device__ __forceinline__ bool lex_lt(float v, int i, float bv, int bi) {
    return (v < bv) || (v == bv && i < bi);
}

// ---------------------------------------------------------------------------
// Kernel 1: transpose [B,C,N] -> [B,N,C]  + emit bf16 MFMA fragments.
// Fragment layout: Xf[b][g][t][lane][8]  (g=n/32, t=k-chunk of 16, 1KB blocks)
//   lane l holds row g*32+(l&31), k = t*16 + (l>>5)*8 + e.
// ---------------------------------------------------------------------------
__global__ __launch_bounds__(256) void k_transpose(const float* __restrict__ fm,
                                                   float* __restrict__ nodes,
                                                   unsigned short* __restrict__ Xf) {
    __shared__ float tile[32][33];   // [c_local][n_local]
    int b  = blockIdx.z;
    int n0 = blockIdx.x * 32;
    int c0 = blockIdx.y * 32;
    int tx = threadIdx.x, ty = threadIdx.y;
    const float* src = fm + (size_t)b * C_ * N_;
    float* dst = nodes + (size_t)b * N_ * C_;
    #pragma unroll
    for (int cc = 0; cc < 32; cc += 8)
        tile[cc + ty][tx] = src[(size_t)(c0 + cc + ty) * N_ + n0 + tx];
    __syncthreads();
    #pragma unroll
    for (int nn = 0; nn < 32; nn += 8)
        dst[(size_t)(n0 + nn + ty) * C_ + c0 + tx] = tile[tx][nn + ty];

    // fragment emission (waves 0,1)
    int flat = ty * 32 + tx;
    int wv = flat >> 6, lane = flat & 63;
    if (wv < 2) {
        int t   = 2 * blockIdx.y + wv;
        int l31 = lane & 31, lh = lane >> 5;
        u16x8 o;
        #pragma unroll
        for (int e = 0; e < 8; ++e)
            o[e] = f2bf(tile[wv * 16 + lh * 8 + e][l31]);
        unsigned short* df = Xf + (((size_t)b * NG + blockIdx.x) * NT + t) * FRAG + lane * 8;
        *(u16x8*)df = o;
    }
}

// ---------------------------------------------------------------------------
// Kernel 2: sq[b,n] = sum_c fm[b,c,n]^2, and write the t=16 augment fragment:
//   [e1, e2, +512, 0...]  (e1+e2 ~= -sq/2; +512 biases S' positive so the raw
//   IEEE bit pattern is the sortable key -- f2sort eliminated in kernel 3).
// ---------------------------------------------------------------------------
__global__ __launch_bounds__(256) void k_sq(const float* __restrict__ fm,
                                            float* __restrict__ sq,
                                            unsigned short* __restrict__ Xf) {
    int b = blockIdx.y;
    int n = blockIdx.x * 256 + threadIdx.x;
    const float* src = fm + (size_t)b * C_ * N_ + n;
    float s = 0.f;
    for (int c = 0; c < C_; ++c) { float v = src[(size_t)c * N_]; s = fmaf(v, v, s); }
    sq[b * N_ + n] = s;

    float sh = -0.5f * s;
    unsigned short e1 = f2bf(sh);
    unsigned short e2 = f2bf(sh - bf2f(e1));
    int g = n >> 5, l = n & 31;
    unsigned short* df = Xf + (((size_t)b * NG + g) * NT + 16) * FRAG + l * 8;
    u16x8 o = (u16x8){0, 0, 0, 0, 0, 0, 0, 0};
    o[0] = e1; o[1] = e2; o[2] = 0x4400;   // bf16(512.0)
    *(u16x8*)df = o;
    u16x8 z = (u16x8){0, 0, 0, 0, 0, 0, 0, 0};
    *(u16x8*)(df + 32 * 8) = z;
}

// ---------------------------------------------------------------------------
// Kernel 3: MFMA prefilter, 256-thr / 1-i-group blocks (occupancy edition).
// Grid: 1152 1D blocks = 8 * 144; wgid = (bid&7)*144 + bid>>3 clusters two
// samples per XCD (2.5 MB Xf working set < 4 MB L2).
// Waves: wj = wave (4-way j-phase); lane: l31 = i-col, lh = j-row half.
// S'' = dot - sqj/2 + 512 > 0 always => packed = (bits & 0xFFFFF000) |
// (4095 - j); unsigned-greater == (larger S', tie -> smaller j).
// Per-lane branchless top-10; snapshot lh-merge; 4 wj-lists -> top-20.
// NOTE: plain launch_bounds, no min-occupancy arg (round-3 spill lesson).
// ---------------------------------------------------------------------------
__global__ __launch_bounds__(256) void k_knn_mfma(const unsigned short* __restrict__ Xf,
                                                  int* __restrict__ pi_pre) {
    __shared__ unsigned int ms[4][32][MPRE];      // [wj][col][q] = 5 KB

    int bid  = blockIdx.x;                        // 1152 = 8 * 144
    int wgid = (bid & 7) * 144 + (bid >> 3);      // bijective XCD swizzle
    int b    = wgid / NG;
    int ig   = wgid % NG;                         // i-group 0..71

    int tid = threadIdx.x;
    int wj = tid >> 6, lane = tid & 63;           // wj 0..3
    int l31 = lane & 31, lh = lane >> 5;

    const unsigned short* Xb = Xf + (size_t)b * NG * NT * FRAG;

    bf16x8 bfr[16];
    const unsigned short* ibase = Xb + (size_t)ig * NT * FRAG + lane * 8;
    #pragma unroll
    for (int t = 0; t < 16; ++t) bfr[t] = *(const bf16x8*)(ibase + t * FRAG);
    short one = (lh == 0) ? (short)0x3F80 : (short)0;
    bf16x8 bc = (bf16x8){one, one, one, 0, 0, 0, 0, 0};   // picks e1+e2+512

    int I0 = ig * 32 + l31;

    unsigned int best[MPRE];
    #pragma unroll
    for (int q = 0; q < MPRE; ++q) best[q] = 0u;

    for (int jt = 0; jt < 18; ++jt) {
        int gj = jt * 4 + wj;                     // covers 0..71 across waves
        const unsigned short* ab = Xb + (size_t)gj * NT * FRAG + lane * 8;

        f32x16 acc;
        #pragma unroll
        for (int r = 0; r < 16; ++r) acc[r] = 0.f;

        #pragma unroll
        for (int t = 0; t < 16; ++t) {
            bf16x8 af = *(const bf16x8*)(ab + t * FRAG);
            acc = __builtin_amdgcn_mfma_f32_32x32x16_bf16(af, bfr[t], acc, 0, 0, 0);
        }
        {
            bf16x8 af = *(const bf16x8*)(ab + 16 * FRAG);
            acc = __builtin_amdgcn_mfma_f32_32x32x16_bf16(af, bc, acc, 0, 0, 0);
        }

        int j0 = gj * 32;
        int idxbase = 4095 - j0 - 4 * lh;         // idx' = idxbase - cr (12 bits)
        #pragma unroll
        for (int r = 0; r < 16; ++r) {
            int cr = (r & 3) + 8 * (r >> 2);
            int gjrow = j0 + cr + 4 * lh;
            // S''>0 -> raw bits are order-preserving; no sign fixup needed
            unsigned int p = (__float_as_uint(acc[r]) & 0xFFFFF000u)
                           | (unsigned int)(idxbase - cr);
            p = (gjrow == I0) ? 0u : p;           // self-exclusion
            #pragma unroll
            for (int q = 0; q < MPRE; ++q) {      // branchless sorted-desc insert
                unsigned int hi = p > best[q] ? p : best[q];
                unsigned int lo = p > best[q] ? best[q] : p;
                best[q] = hi; p = lo;
            }
        }
    }

    // in-wave lh merge: snapshot partner's ORIGINAL list first, then insert
    {
        unsigned int part[MPRE];
        #pragma unroll
        for (int q = 0; q < MPRE; ++q)
            part[q] = (unsigned int)__shfl_xor((int)best[q], 32);
        #pragma unroll
        for (int q = 0; q < MPRE; ++q) {
            unsigned int p = part[q];
            #pragma unroll
            for (int s = 0; s < MPRE; ++s) {
                unsigned int hi = p > best[s] ? p : best[s];
                unsigned int lo = p > best[s] ? best[s] : p;
                best[s] = hi; p = lo;
            }
        }
    }
    if (lh == 0) {
        #pragma unroll
        for (int q = 0; q < MPRE; ++q) ms[wj][l31][q] = best[q];
    }
    __syncthreads();

    // final merge: 32 threads, one i-col each; 4 wj-lists x 10 -> top-20
    if (tid < 32) {
        unsigned int mb[NCAND];
        #pragma unroll
        for (int q = 0; q < NCAND; ++q) mb[q] = 0u;
        for (int wjj = 0; wjj < 4; ++wjj) {
            #pragma unroll
            for (int qq = 0; qq < MPRE; ++qq) {
                unsigned int p = ms[wjj][tid][qq];
                #pragma unroll
                for (int q = 0; q < NCAND; ++q) {
                    unsigned int hi = p > mb[q] ? p : mb[q];
                    unsigned int lo = p > mb[q] ? mb[q] : p;
                    mb[q] = hi; p = lo;
                }
            }
        }
        int i_g = ig * 32 + tid;
        int* dst = pi_pre + ((size_t)b * N_ + i_g) * NCAND;
        #pragma unroll
        for (int q = 0; q < NCAND; ++q) dst[q] = 4095 - (int)(mb[q] & 0xFFFu);
    }
}

// ---------------------------------------------------------------------------
// Kernel 4: FUSED exact rerank + aggregate + residual + LayerNorm + write.
// 16 rows/block (4 waves x 4 rows). Per row:
//   phase 1 (rerank): 4x16-lane groups compute candidate dots (4 float4/lane,
//     4-step butterfly), d2 staged in per-wave LDS (same-wave, no barrier),
//     uniform lex insertion -> every lane holds top-8 (replicated).
//   phase 2 (agg+LN): lane owns 4 channels; gather 8 knn rows (L1/L2-hot
//     from phase 1) + grid nbrs + self; 64-lane butterfly mean/var; stage.
// Single barrier, then round-10-style transposed write (64-B chunks/thread).
// ---------------------------------------------------------------------------
__global__ __launch_bounds__(256) void k_rerank_agg(const float* __restrict__ nodes,
                                                    const float* __restrict__ sq,
                                                    const int* __restrict__ pi_pre,
                                                    const float* __restrict__ gamma,
                                                    const float* __restrict__ beta,
                                                    float* __restrict__ out) {
    __shared__ float d2s[4][NCAND];
    __shared__ int   jss[4][NCAND];
    __shared__ float ytile[16][C_ + 1];

    int tid  = threadIdx.x;
    int wv   = tid >> 6, lane = tid & 63;
    int g    = lane >> 4, m = lane & 15;
    int row0 = blockIdx.x * 16;                   // flat row base (same b for all 16)
    int b    = row0 / N_;
    int i0   = row0 - b * N_;
    const float* Xb = nodes + (size_t)b * N_ * C_;

    float4 g4 = *(const float4*)&gamma[lane * 4];
    float4 b4 = *(const float4*)&beta[lane * 4];

    for (int rr = 0; rr < 4; ++rr) {
        int i    = i0 + wv * 4 + rr;
        int rowg = b * N_ + i;

        // ---- phase 1: exact fp32 rerank of 20 candidates ----
        const float* xi = Xb + (size_t)i * C_;
        float4 xiv[4];
        #pragma unroll
        for (int p = 0; p < 4; ++p) xiv[p] = *(const float4*)&xi[p * 64 + m * 4];
        float sqi = sq[rowg];
        const int* cand = pi_pre + (size_t)rowg * NCAND;

        for (int it = 0; it < 5; ++it) {
            int c = it * 4 + g;
            int j = cand[c];
            bool valid = (unsigned)j < (unsigned)N_;
            int jc = valid ? j : 0;
            const float* xj = Xb + (size_t)jc * C_;
            float p = 0.f;
            #pragma unroll
            for (int pp = 0; pp < 4; ++pp) {
                float4 v = *(const float4*)&xj[pp * 64 + m * 4];
                p = fmaf(xiv[pp].x, v.x, p);
                p = fmaf(xiv[pp].y, v.y, p);
                p = fmaf(xiv[pp].z, v.z, p);
                p = fmaf(xiv[pp].w, v.w, p);
            }
            p += __shfl_xor(p, 1);
            p += __shfl_xor(p, 2);
            p += __shfl_xor(p, 4);
            p += __shfl_xor(p, 8);
            if (m == 0) {
                d2s[wv][c] = valid ? (sqi + sq[b * N_ + jc] - 2.f * p) : 3.4e38f;
                jss[wv][c] = valid ? j : 0x7fffffff;
            }
        }

        float bd[KNN]; int bj[KNN];
        #pragma unroll
        for (int q = 0; q < KNN; ++q) { bd[q] = 3.4e38f; bj[q] = 0x7fffffff; }
        for (int s = 0; s < NCAND; ++s) {
            float v = d2s[wv][s]; int jx = jss[wv][s];
            if (lex_lt(v, jx, bd[KNN - 1], bj[KNN - 1])) {
                float cv = v; int ci = jx;
                #pragma unroll
                for (int q = 0; q < KNN; ++q) {
                    if (lex_lt(cv, ci, bd[q], bj[q])) {
                        float tv = bd[q]; bd[q] = cv; cv = tv;
                        int tx2 = bj[q]; bj[q] = ci; ci = tx2;
                    }
                }
            }
        }

        // ---- phase 2: aggregate (grid + knn) mean + residual + LN ----
        int x_ = i % W_;
        int y_ = i / W_;
        float s0 = 0.f, s1 = 0.f, s2 = 0.f, s3 = 0.f;
        int cnt = KNN;
        #define ADDROW(J) { float4 v = *(const float4*)&Xb[(size_t)(J) * C_ + lane * 4]; \
                            s0 += v.x; s1 += v.y; s2 += v.z; s3 += v.w; }
        if (x_ > 0)      { ADDROW(i - 1);  cnt++; }
        if (x_ < W_ - 1) { ADDROW(i + 1);  cnt++; }
        if (y_ > 0)      { ADDROW(i - W_); cnt++; }
        if (y_ < H_ - 1) { ADDROW(i + W_); cnt++; }
        #pragma unroll
        for (int k = 0; k < KNN; ++k) ADDROW(bj[k]);
        #undef ADDROW

        float4 xi4 = *(const float4*)&Xb[(size_t)i * C_ + lane * 4];
        float ic = 1.f / (float)cnt;
        float y0 = s0 * ic + xi4.x;
        float y1 = s1 * ic + xi4.y;
        float y2 = s2 * ic + xi4.z;
        float y3 = s3 * ic + xi4.w;

        float rx = y0 + y1 + y2 + y3;
        float ry = y0 * y0 + y1 * y1 + y2 * y2 + y3 * y3;
        #pragma unroll
        for (int mm = 1; mm < 64; mm <<= 1) {
            rx += __shfl_xor(rx, mm);
            ry += __shfl_xor(ry, mm);
        }
        float mu  = rx * (1.f / C_);
        float var = ry * (1.f / C_) - mu * mu;
        float inv = rsqrtf(var + 1e-5f);

        int ii = wv * 4 + rr;
        ytile[ii][lane * 4 + 0] = (y0 - mu) * inv * g4.x + b4.x;
        ytile[ii][lane * 4 + 1] = (y1 - mu) * inv * g4.y + b4.y;
        ytile[ii][lane * 4 + 2] = (y2 - mu) * inv * g4.z + b4.z;
        ytile[ii][lane * 4 + 3] = (y3 - mu) * inv * g4.w + b4.w;
    }
    __syncthreads();

    float* op = out + (size_t)b * C_ * N_ + (size_t)tid * N_ + i0;
    float vv[16];
    #pragma unroll
    for (int ii = 0; ii < 16; ++ii) vv[ii] = ytile[ii][tid];
    #pragma unroll
    for (int q = 0; q < 4; ++q) {
        float4 w;
        w.x = vv[q * 4 + 0]; w.y = vv[q * 4 + 1];
        w.z = vv[q * 4 + 2]; w.w = vv[q * 4 + 3];
        *(float4*)&op[q * 4] = w;
    }
}

// ---------------------------------------------------------------------------
extern "C" void kernel_launch(void* const* d_in, const int* in_sizes, int n_in,
                              void* d_out, int out_size, void* d_ws, size_t ws_size,
                              hipStream_t stream) {
    const float* fm    = (const float*)d_in[0];
    const float* gamma = (const float*)d_in[1];
    const float* beta  = (const float*)d_in[2];
    float* out = (float*)d_out;

    char* ws = (char*)d_ws;
    size_t off = 0;
    float* nodes = (float*)(ws + off); off += (size_t)B_ * N_ * C_ * sizeof(float);           // 37.75 MB
    float* sq    = (float*)(ws + off); off += (size_t)B_ * N_ * sizeof(float);                // 0.14 MB
    unsigned short* Xf = (unsigned short*)(ws + off);
    off += (size_t)B_ * NG * NT * FRAG * sizeof(unsigned short);                              // 20.05 MB
    int* pi_pre = (int*)(ws + off);
    off += (size_t)B_ * N_ * NCAND * sizeof(int);                                             // 2.95 MB

    k_transpose<<<dim3(N_ / 32, C_ / 32, B_), dim3(32, 8), 0, stream>>>(fm, nodes, Xf);
    k_sq<<<dim3(N_ / 256, B_), 256, 0, stream>>>(fm, sq, Xf);
    k_knn_mfma<<<(B_ * NG), 256, 0, stream>>>(Xf, pi_pre);
    k_rerank_agg<<<(B_ * N_) / 16, 256, 0, stream>>>(nodes, sq, pi_pre, gamma, beta, out);
}